// Round 1
// baseline (326.366 us; speedup 1.0000x reference)
//
#include <hip/hip_runtime.h>
#include <hip/hip_bf16.h>

#define TT 2048

typedef __attribute__((ext_vector_type(8))) short bf16x8;
typedef __attribute__((ext_vector_type(4))) float f32x4;

__device__ __forceinline__ short f2b(float f) {
  union { float f; unsigned u; } a; a.f = f;
  unsigned r = a.u + 0x7fffu + ((a.u >> 16) & 1u);
  return (short)(r >> 16);
}
__device__ __forceinline__ float b2f(short s) {
  union { unsigned u; float f; } a; a.u = ((unsigned)(unsigned short)s) << 16;
  return a.f;
}

// dst[n][k] = bf16(src[k][n]);  K fixed at 512
__global__ __launch_bounds__(256) void tcast_kernel(const float* __restrict__ src,
                                                    short* __restrict__ dst, int N) {
  int idx = blockIdx.x * 256 + threadIdx.x;
  int n = idx >> 9, kk = idx & 511;
  if (n < N) dst[idx] = f2b(src[(size_t)kk * N + n]);
}

// LayerNorm rows of 512, fp32 in, bf16 out
__global__ __launch_bounds__(256) void ln_kernel(const float* __restrict__ x,
                                                 const float* __restrict__ w,
                                                 const float* __restrict__ b,
                                                 short* __restrict__ h) {
  const int row = blockIdx.x;
  const int tid = threadIdx.x;
  const float2 v = *reinterpret_cast<const float2*>(x + (size_t)row * 512 + tid * 2);
  float s = v.x + v.y;
  float sq = v.x * v.x + v.y * v.y;
  for (int off = 1; off < 64; off <<= 1) { s += __shfl_xor(s, off); sq += __shfl_xor(sq, off); }
  __shared__ float red[8];
  const int wv = tid >> 6;
  if ((tid & 63) == 0) { red[wv] = s; red[wv + 4] = sq; }
  __syncthreads();
  s = red[0] + red[1] + red[2] + red[3];
  sq = red[4] + red[5] + red[6] + red[7];
  const float mu = s * (1.0f / 512.0f);
  const float var = sq * (1.0f / 512.0f) - mu * mu;
  const float inv = rsqrtf(var + 1e-5f);
  const float2 wv2 = *reinterpret_cast<const float2*>(w + tid * 2);
  const float2 bv2 = *reinterpret_cast<const float2*>(b + tid * 2);
  const float h0 = (v.x - mu) * inv * wv2.x + bv2.x;
  const float h1 = (v.y - mu) * inv * wv2.y + bv2.y;
  unsigned u = (unsigned)(unsigned short)f2b(h0) | ((unsigned)(unsigned short)f2b(h1) << 16);
  *reinterpret_cast<unsigned*>(h + (size_t)row * 512 + tid * 2) = u;
}

// 128x128 tile GEMM, A[M][512] bf16 row-major, Bt[N][512] bf16 (B transposed).
// EPI=0: scatter into q[bh][t][d], k[bh][t][d], vt[bh][d][t] (bf16) with bias
// EPI=1: out[row][col] = acc + bias (f32)
template <int EPI>
__global__ __launch_bounds__(256) void gemm128_kernel(const short* __restrict__ A,
                                                      const short* __restrict__ Bt,
                                                      const float* __restrict__ bias,
                                                      void* __restrict__ o0,
                                                      void* __restrict__ o1,
                                                      void* __restrict__ o2) {
  __shared__ short As[128][72];
  __shared__ short Bs[128][72];
  const int tid = threadIdx.x;
  const int lane = tid & 63, wave = tid >> 6;
  const int lr = lane & 15, lg = lane >> 4;
  const int wm = wave >> 1, wn = wave & 1;
  const int m0 = blockIdx.x * 128, n0 = blockIdx.y * 128;
  const int sr = tid >> 3, sc = (tid & 7) * 8;

  f32x4 acc[4][4] = {};

  for (int k0 = 0; k0 < 512; k0 += 64) {
    for (int i = 0; i < 4; ++i) {
      const int r = sr + 32 * i;
      *reinterpret_cast<bf16x8*>(&As[r][sc]) =
          *reinterpret_cast<const bf16x8*>(A + (size_t)(m0 + r) * 512 + k0 + sc);
      *reinterpret_cast<bf16x8*>(&Bs[r][sc]) =
          *reinterpret_cast<const bf16x8*>(Bt + (size_t)(n0 + r) * 512 + k0 + sc);
    }
    __syncthreads();
    for (int ks = 0; ks < 2; ++ks) {
      bf16x8 af[4], bfr[4];
      for (int m = 0; m < 4; ++m)
        af[m] = *reinterpret_cast<const bf16x8*>(&As[wm * 64 + m * 16 + lr][ks * 32 + lg * 8]);
      for (int n = 0; n < 4; ++n)
        bfr[n] = *reinterpret_cast<const bf16x8*>(&Bs[wn * 64 + n * 16 + lr][ks * 32 + lg * 8]);
      for (int m = 0; m < 4; ++m)
        for (int n = 0; n < 4; ++n)
          acc[m][n] = __builtin_amdgcn_mfma_f32_16x16x32_bf16(af[m], bfr[n], acc[m][n], 0, 0, 0);
    }
    __syncthreads();
  }

  for (int m = 0; m < 4; ++m) {
    for (int n = 0; n < 4; ++n) {
      for (int j = 0; j < 4; ++j) {
        const int row = m0 + wm * 64 + m * 16 + lg * 4 + j;
        const int col = n0 + wn * 64 + n * 16 + lr;
        const float val = acc[m][n][j] + bias[col];
        if (EPI == 0) {
          const int which = col >> 9;
          const int rem = col & 511;
          const int hh = rem >> 6, d = rem & 63;
          const int bb = row >> 11, t = row & 2047;
          const int bh = bb * 8 + hh;
          short* qp = (short*)o0; short* kp = (short*)o1; short* vtp = (short*)o2;
          if (which == 0)      qp[((size_t)bh * TT + t) * 64 + d] = f2b(val);
          else if (which == 1) kp[((size_t)bh * TT + t) * 64 + d] = f2b(val);
          else                 vtp[((size_t)bh * 64 + d) * TT + t] = f2b(val);
        } else {
          float* outp = (float*)o0;
          outp[(size_t)row * 512 + col] = val;
        }
      }
    }
  }
}

// RoPE in-place on q and k, layout [bh][t][64]
__global__ __launch_bounds__(256) void rope_kernel(short* __restrict__ q, short* __restrict__ k) {
  const unsigned idx = blockIdx.x * 256 + threadIdx.x;  // 64*2048*32 total
  const int i = idx & 31;
  const unsigned bt = idx >> 5;
  const int t = bt & 2047;
  const float inv_freq = __expf(-(float)i * (9.210340371976184f / 32.0f));  // 10000^(-i/32)
  const float ang = (float)t * inv_freq;
  float sv, cv;
  sincosf(ang, &sv, &cv);
  const size_t base = (size_t)bt * 64;
  {
    const float x1 = b2f(q[base + i]), x2 = b2f(q[base + i + 32]);
    q[base + i]      = f2b(x1 * cv - x2 * sv);
    q[base + i + 32] = f2b(x2 * cv + x1 * sv);
  }
  {
    const float x1 = b2f(k[base + i]), x2 = b2f(k[base + i + 32]);
    k[base + i]      = f2b(x1 * cv - x2 * sv);
    k[base + i + 32] = f2b(x2 * cv + x1 * sv);
  }
}

// Flash attention: grid (T/64, B*H), 4 waves, each wave owns 16 q rows.
// q,k: [bh][t][64] bf16; vt: [bh][d][t] bf16; o: [b*T + t][h*64 + d] bf16
__global__ __launch_bounds__(256) void attn_kernel(const short* __restrict__ q,
                                                   const short* __restrict__ k,
                                                   const short* __restrict__ vt,
                                                   const unsigned char* __restrict__ mask,
                                                   short* __restrict__ o) {
  __shared__ short Ks[64][72];
  __shared__ short Vts[64][72];
  __shared__ short Ps[4][16][72];
  __shared__ float msk[64];
  const int tid = threadIdx.x;
  const int lane = tid & 63, wave = tid >> 6;
  const int lr = lane & 15, lg = lane >> 4;
  const int qt = blockIdx.x, bh = blockIdx.y;
  const int bb = bh >> 3, hh = bh & 7;
  const int q0 = qt * 64 + wave * 16;
  const size_t bhT = (size_t)bh * TT;

  bf16x8 aq[2];
  for (int ks = 0; ks < 2; ++ks)
    aq[ks] = *reinterpret_cast<const bf16x8*>(q + (bhT + q0 + lr) * 64 + ks * 32 + lg * 8);

  f32x4 o_acc[4] = {};
  float m_run[4], l_run[4];
  for (int j = 0; j < 4; ++j) { m_run[j] = -1e30f; l_run[j] = 0.0f; }

  const int sr = tid >> 3, sc = (tid & 7) * 8;

  for (int kt = 0; kt < TT / 64; ++kt) {
    for (int i = 0; i < 2; ++i) {
      const int r = sr + 32 * i;
      *reinterpret_cast<bf16x8*>(&Ks[r][sc]) =
          *reinterpret_cast<const bf16x8*>(k + (bhT + kt * 64 + r) * 64 + sc);
      *reinterpret_cast<bf16x8*>(&Vts[r][sc]) =
          *reinterpret_cast<const bf16x8*>(vt + ((size_t)bh * 64 + r) * TT + kt * 64 + sc);
    }
    if (tid < 64) msk[tid] = mask[(size_t)bb * TT + kt * 64 + tid] ? -1e30f : 0.0f;
    __syncthreads();

    // S = Q K^T for this wave's 16 q rows x 64 keys
    f32x4 sacc[4] = {};
    for (int ks = 0; ks < 2; ++ks) {
      for (int n = 0; n < 4; ++n) {
        const bf16x8 bk = *reinterpret_cast<const bf16x8*>(&Ks[n * 16 + lr][ks * 32 + lg * 8]);
        sacc[n] = __builtin_amdgcn_mfma_f32_16x16x32_bf16(aq[ks], bk, sacc[n], 0, 0, 0);
      }
    }

    float sv[4][4], pmax[4];
    for (int j = 0; j < 4; ++j) pmax[j] = -1e30f;
    for (int n = 0; n < 4; ++n) {
      const float mm = msk[n * 16 + lr];
      for (int j = 0; j < 4; ++j) {
        const float xv = sacc[n][j] * 0.125f + mm;
        sv[n][j] = xv;
        pmax[j] = fmaxf(pmax[j], xv);
      }
    }
    for (int j = 0; j < 4; ++j)
      for (int off = 1; off < 16; off <<= 1)
        pmax[j] = fmaxf(pmax[j], __shfl_xor(pmax[j], off));

    float newm[4], pscale[4], rsum[4];
    for (int j = 0; j < 4; ++j) {
      newm[j] = fmaxf(m_run[j], pmax[j]);
      pscale[j] = __expf(m_run[j] - newm[j]);
      m_run[j] = newm[j];
      rsum[j] = 0.0f;
    }
    for (int n = 0; n < 4; ++n) {
      for (int j = 0; j < 4; ++j) {
        const float p = __expf(sv[n][j] - newm[j]);
        rsum[j] += p;
        Ps[wave][lg * 4 + j][n * 16 + lr] = f2b(p);
      }
    }
    for (int j = 0; j < 4; ++j) {
      for (int off = 1; off < 16; off <<= 1) rsum[j] += __shfl_xor(rsum[j], off);
      l_run[j] = l_run[j] * pscale[j] + rsum[j];
    }
    for (int dt = 0; dt < 4; ++dt) {
      f32x4 t = o_acc[dt];
      for (int j = 0; j < 4; ++j) t[j] *= pscale[j];
      o_acc[dt] = t;
    }
    // O += P V  (V^T in LDS so B-frags are contiguous)
    for (int ks = 0; ks < 2; ++ks) {
      const bf16x8 ap = *reinterpret_cast<const bf16x8*>(&Ps[wave][lr][ks * 32 + lg * 8]);
      for (int dt = 0; dt < 4; ++dt) {
        const bf16x8 bv = *reinterpret_cast<const bf16x8*>(&Vts[dt * 16 + lr][ks * 32 + lg * 8]);
        o_acc[dt] = __builtin_amdgcn_mfma_f32_16x16x32_bf16(ap, bv, o_acc[dt], 0, 0, 0);
      }
    }
    __syncthreads();
  }

  for (int j = 0; j < 4; ++j) {
    const float invl = 1.0f / l_run[j];
    const size_t row_g = (size_t)bb * TT + q0 + lg * 4 + j;
    for (int dt = 0; dt < 4; ++dt)
      o[row_g * 512 + hh * 64 + dt * 16 + lr] = f2b(o_acc[dt][j] * invl);
  }
}

extern "C" void kernel_launch(void* const* d_in, const int* in_sizes, int n_in,
                              void* d_out, int out_size, void* d_ws, size_t ws_size,
                              hipStream_t stream) {
  (void)in_sizes; (void)n_in; (void)out_size; (void)ws_size;
  const float* x = (const float*)d_in[0];
  const unsigned char* mask = (const unsigned char*)d_in[1];
  const float* ln_w = (const float*)d_in[2];
  const float* ln_b = (const float*)d_in[3];
  const float* w_qkv = (const float*)d_in[4];
  const float* b_qkv = (const float*)d_in[5];
  const float* w_o = (const float*)d_in[6];
  const float* b_o = (const float*)d_in[7];
  float* out = (float*)d_out;

  char* ws = (char*)d_ws;
  short* h_buf = (short*)(ws);                 // 16384*512 bf16 = 16 MB; reused as attn_out
  short* wqkvT = (short*)(ws + 16777216);      // 1536*512 bf16
  short* woT   = (short*)(ws + 18350080);      // 512*512 bf16
  short* q_ws  = (short*)(ws + 18874368);      // [64][2048][64] bf16
  short* k_ws  = (short*)(ws + 35651584);      // [64][2048][64] bf16
  short* vt_ws = (short*)(ws + 52428800);      // [64][64][2048] bf16
  // total ws use: 69,206,016 bytes

  hipLaunchKernelGGL(tcast_kernel, dim3(3072), dim3(256), 0, stream, w_qkv, wqkvT, 1536);
  hipLaunchKernelGGL(tcast_kernel, dim3(1024), dim3(256), 0, stream, w_o, woT, 512);
  hipLaunchKernelGGL(ln_kernel, dim3(16384), dim3(256), 0, stream, x, ln_w, ln_b, h_buf);
  hipLaunchKernelGGL((gemm128_kernel<0>), dim3(128, 12), dim3(256), 0, stream,
                     h_buf, wqkvT, b_qkv, (void*)q_ws, (void*)k_ws, (void*)vt_ws);
  hipLaunchKernelGGL(rope_kernel, dim3(16384), dim3(256), 0, stream, q_ws, k_ws);
  hipLaunchKernelGGL(attn_kernel, dim3(32, 64), dim3(256), 0, stream,
                     q_ws, k_ws, vt_ws, mask, h_buf);
  hipLaunchKernelGGL((gemm128_kernel<1>), dim3(128, 4), dim3(256), 0, stream,
                     h_buf, woT, b_o, (void*)out, nullptr, nullptr);
}

// Round 2
// 233.360 us; speedup vs baseline: 1.3986x; 1.3986x over previous
//
#include <hip/hip_runtime.h>
#include <hip/hip_bf16.h>

#define TT 2048

typedef __attribute__((ext_vector_type(8))) short bf16x8;
typedef __attribute__((ext_vector_type(4))) float f32x4;
typedef __attribute__((ext_vector_type(16))) float f32x16;

__device__ __forceinline__ short f2b(float f) {
  union { float f; unsigned u; } a; a.f = f;
  unsigned r = a.u + 0x7fffu + ((a.u >> 16) & 1u);
  return (short)(r >> 16);
}
__device__ __forceinline__ float b2f(short s) {
  union { unsigned u; float f; } a; a.u = ((unsigned)(unsigned short)s) << 16;
  return a.f;
}
__device__ __forceinline__ unsigned cvtpk(float lo, float hi) {
  unsigned r;
  asm("v_cvt_pk_bf16_f32 %0, %1, %2" : "=v"(r) : "v"(lo), "v"(hi));
  return r;
}
// exchange high-32 lanes of a with low-32 lanes of b (permlane32_swap semantics)
__device__ __forceinline__ void swap_halves(unsigned &a, unsigned &b, bool hi) {
  unsigned as = (unsigned)__shfl_xor((int)a, 32);
  unsigned bs = (unsigned)__shfl_xor((int)b, 32);
  unsigned na = hi ? bs : a;
  unsigned nb = hi ? b : as;
  a = na; b = nb;
}

// p16: 16 f32 P-values (one 32-row S^T fragment) -> two PV A-frags (ks, ks+1)
__device__ __forceinline__ void p_to_frags(const float* p16, bool hi, bf16x8* f0, bf16x8* f1) {
  unsigned A[4][2];
#pragma unroll
  for (int u = 0; u < 4; ++u)
#pragma unroll
    for (int c = 0; c < 2; ++c)
      A[u][c] = cvtpk(p16[4 * u + 2 * c], p16[4 * u + 2 * c + 1]);
  swap_halves(A[0][0], A[1][0], hi);
  swap_halves(A[0][1], A[1][1], hi);
  swap_halves(A[2][0], A[3][0], hi);
  swap_halves(A[2][1], A[3][1], hi);
  union { unsigned u[4]; bf16x8 v; } r0, r1;
  r0.u[0] = A[0][0]; r0.u[1] = A[0][1]; r0.u[2] = A[1][0]; r0.u[3] = A[1][1];
  r1.u[0] = A[2][0]; r1.u[1] = A[2][1]; r1.u[2] = A[3][0]; r1.u[3] = A[3][1];
  *f0 = r0.v; *f1 = r1.v;
}

__device__ __forceinline__ bf16x8 lds16(const short* base, int row, int cb) {
  return *reinterpret_cast<const bf16x8*>(
      reinterpret_cast<const char*>(base) + row * 128 + (cb ^ ((row & 7) << 4)));
}
__device__ __forceinline__ void lds16w(short* base, int row, int cb, bf16x8 v) {
  *reinterpret_cast<bf16x8*>(
      reinterpret_cast<char*>(base) + row * 128 + (cb ^ ((row & 7) << 4))) = v;
}

// dst[n][k] = bf16(src[k][n]);  K fixed at 512
__global__ __launch_bounds__(256) void tcast_kernel(const float* __restrict__ src,
                                                    short* __restrict__ dst, int N) {
  int idx = blockIdx.x * 256 + threadIdx.x;
  int n = idx >> 9, kk = idx & 511;
  if (n < N) dst[idx] = f2b(src[(size_t)kk * N + n]);
}

// LayerNorm rows of 512, fp32 in, bf16 out
__global__ __launch_bounds__(256) void ln_kernel(const float* __restrict__ x,
                                                 const float* __restrict__ w,
                                                 const float* __restrict__ b,
                                                 short* __restrict__ h) {
  const int row = blockIdx.x;
  const int tid = threadIdx.x;
  const float2 v = *reinterpret_cast<const float2*>(x + (size_t)row * 512 + tid * 2);
  float s = v.x + v.y;
  float sq = v.x * v.x + v.y * v.y;
  for (int off = 1; off < 64; off <<= 1) { s += __shfl_xor(s, off); sq += __shfl_xor(sq, off); }
  __shared__ float red[8];
  const int wv = tid >> 6;
  if ((tid & 63) == 0) { red[wv] = s; red[wv + 4] = sq; }
  __syncthreads();
  s = red[0] + red[1] + red[2] + red[3];
  sq = red[4] + red[5] + red[6] + red[7];
  const float mu = s * (1.0f / 512.0f);
  const float var = sq * (1.0f / 512.0f) - mu * mu;
  const float inv = rsqrtf(var + 1e-5f);
  const float2 wv2 = *reinterpret_cast<const float2*>(w + tid * 2);
  const float2 bv2 = *reinterpret_cast<const float2*>(b + tid * 2);
  const float h0 = (v.x - mu) * inv * wv2.x + bv2.x;
  const float h1 = (v.y - mu) * inv * wv2.y + bv2.y;
  unsigned u = (unsigned)(unsigned short)f2b(h0) | ((unsigned)(unsigned short)f2b(h1) << 16);
  *reinterpret_cast<unsigned*>(h + (size_t)row * 512 + tid * 2) = u;
}

// 128x128 tile GEMM, A[M][512] bf16 row-major, Bt[N][512] bf16 (B transposed).
template <int EPI>
__global__ __launch_bounds__(256) void gemm128_kernel(const short* __restrict__ A,
                                                      const short* __restrict__ Bt,
                                                      const float* __restrict__ bias,
                                                      void* __restrict__ o0,
                                                      void* __restrict__ o1,
                                                      void* __restrict__ o2) {
  __shared__ short As[128][72];
  __shared__ short Bs[128][72];
  const int tid = threadIdx.x;
  const int lane = tid & 63, wave = tid >> 6;
  const int lr = lane & 15, lg = lane >> 4;
  const int wm = wave >> 1, wn = wave & 1;
  const int m0 = blockIdx.x * 128, n0 = blockIdx.y * 128;
  const int sr = tid >> 3, sc = (tid & 7) * 8;

  f32x4 acc[4][4] = {};

  for (int k0 = 0; k0 < 512; k0 += 64) {
    for (int i = 0; i < 4; ++i) {
      const int r = sr + 32 * i;
      *reinterpret_cast<bf16x8*>(&As[r][sc]) =
          *reinterpret_cast<const bf16x8*>(A + (size_t)(m0 + r) * 512 + k0 + sc);
      *reinterpret_cast<bf16x8*>(&Bs[r][sc]) =
          *reinterpret_cast<const bf16x8*>(Bt + (size_t)(n0 + r) * 512 + k0 + sc);
    }
    __syncthreads();
    for (int ks = 0; ks < 2; ++ks) {
      bf16x8 af[4], bfr[4];
      for (int m = 0; m < 4; ++m)
        af[m] = *reinterpret_cast<const bf16x8*>(&As[wm * 64 + m * 16 + lr][ks * 32 + lg * 8]);
      for (int n = 0; n < 4; ++n)
        bfr[n] = *reinterpret_cast<const bf16x8*>(&Bs[wn * 64 + n * 16 + lr][ks * 32 + lg * 8]);
      for (int m = 0; m < 4; ++m)
        for (int n = 0; n < 4; ++n)
          acc[m][n] = __builtin_amdgcn_mfma_f32_16x16x32_bf16(af[m], bfr[n], acc[m][n], 0, 0, 0);
    }
    __syncthreads();
  }

  for (int m = 0; m < 4; ++m) {
    for (int n = 0; n < 4; ++n) {
      for (int j = 0; j < 4; ++j) {
        const int row = m0 + wm * 64 + m * 16 + lg * 4 + j;
        const int col = n0 + wn * 64 + n * 16 + lr;
        const float val = acc[m][n][j] + bias[col];
        if (EPI == 0) {
          const int which = col >> 9;
          const int rem = col & 511;
          const int hh = rem >> 6, d = rem & 63;
          const int bb = row >> 11, t = row & 2047;
          const int bh = bb * 8 + hh;
          short* qp = (short*)o0; short* kp = (short*)o1; short* vtp = (short*)o2;
          if (which == 0)      qp[((size_t)bh * TT + t) * 64 + d] = f2b(val);
          else if (which == 1) kp[((size_t)bh * TT + t) * 64 + d] = f2b(val);
          else                 vtp[((size_t)bh * 64 + d) * TT + t] = f2b(val);
        } else {
          float* outp = (float*)o0;
          outp[(size_t)row * 512 + col] = val;
        }
      }
    }
  }
}

// RoPE in-place on q and k, layout [bh][t][64]; q additionally scaled by 1/sqrt(64)
__global__ __launch_bounds__(256) void rope_kernel(short* __restrict__ q, short* __restrict__ k) {
  const unsigned idx = blockIdx.x * 256 + threadIdx.x;  // 64*2048*32 total
  const int i = idx & 31;
  const unsigned bt = idx >> 5;
  const int t = bt & 2047;
  const float inv_freq = __expf(-(float)i * (9.210340371976184f / 32.0f));  // 10000^(-i/32)
  const float ang = (float)t * inv_freq;
  float sv, cv;
  sincosf(ang, &sv, &cv);
  const size_t base = (size_t)bt * 64;
  {
    const float x1 = b2f(q[base + i]), x2 = b2f(q[base + i + 32]);
    q[base + i]      = f2b((x1 * cv - x2 * sv) * 0.125f);
    q[base + i + 32] = f2b((x2 * cv + x1 * sv) * 0.125f);
  }
  {
    const float x1 = b2f(k[base + i]), x2 = b2f(k[base + i + 32]);
    k[base + i]      = f2b(x1 * cv - x2 * sv);
    k[base + i + 32] = f2b(x2 * cv + x1 * sv);
  }
}

// Flash attention, swapped-QK^T 32x32x16 structure (m214-style).
// grid (T/128, B*H), 4 waves x 32 q-rows. q,k: [bh][t][64]; vt: [bh][d][t];
// o: [b*T + t][h*64 + d] bf16.
__global__ __launch_bounds__(256) void attn_kernel(const short* __restrict__ q,
                                                   const short* __restrict__ k,
                                                   const short* __restrict__ vt,
                                                   const unsigned char* __restrict__ mask,
                                                   short* __restrict__ o) {
  __shared__ short Ks[64 * 64];
  __shared__ short Vs[64 * 64];
  __shared__ float psc[4][32];
  const int tid = threadIdx.x;
  const int lane = tid & 63, wave = tid >> 6;
  const int l31 = lane & 31, g = lane >> 5;
  const bool hi = (g != 0);
  const int bh = blockIdx.y, bb = bh >> 3, hh = bh & 7;
  const int q0 = blockIdx.x * 128 + wave * 32;
  const size_t bhT = (size_t)bh * TT;

  // Q as B-operand frags: qf[ds] holds Q[q0+l31][16*ds + 8*g + j], j=0..7
  bf16x8 qf[4];
#pragma unroll
  for (int ds = 0; ds < 4; ++ds)
    qf[ds] = *reinterpret_cast<const bf16x8*>(q + (bhT + q0 + l31) * 64 + ds * 16 + g * 8);

  f32x16 oa0 = {}, oa1 = {};
  float m_run = -1e30f, l_run = 0.0f;

  const int srow = tid >> 2;         // 0..63
  const int scb = (tid & 3) * 32;    // byte col in 128B row

  for (int kt = 0; kt < TT / 64; ++kt) {
    // stage K[64][64] and V^T[64 d][64 k] into LDS, XOR-swizzled
    {
      const char* kg = (const char*)(k + (bhT + (size_t)kt * 64 + srow) * 64);
      lds16w(Ks, srow, scb,      *reinterpret_cast<const bf16x8*>(kg + scb));
      lds16w(Ks, srow, scb + 16, *reinterpret_cast<const bf16x8*>(kg + scb + 16));
      const char* vg = (const char*)(vt + ((size_t)bh * 64 + srow) * TT + (size_t)kt * 64);
      lds16w(Vs, srow, scb,      *reinterpret_cast<const bf16x8*>(vg + scb));
      lds16w(Vs, srow, scb + 16, *reinterpret_cast<const bf16x8*>(vg + scb + 16));
    }
    const unsigned char mv = mask[(size_t)bb * TT + kt * 64 + lane];
    __syncthreads();

    // S^T = K Q^T : lane holds S[q=q0+l31][64 keys], split over both halves
    f32x16 s0 = {}, s1 = {};
#pragma unroll
    for (int ds = 0; ds < 4; ++ds) {
      const int cb = ds * 32 + g * 16;
      const bf16x8 ka0 = lds16(Ks, l31, cb);
      const bf16x8 ka1 = lds16(Ks, 32 + l31, cb);
      s0 = __builtin_amdgcn_mfma_f32_32x32x16_bf16(ka0, qf[ds], s0, 0, 0, 0);
      s1 = __builtin_amdgcn_mfma_f32_32x32x16_bf16(ka1, qf[ds], s1, 0, 0, 0);
    }

    float p[32];
#pragma unroll
    for (int r = 0; r < 16; ++r) { p[r] = s0[r]; p[16 + r] = s1[r]; }

    if (__any(mv != 0)) {  // mask slow path (test mask is all-false)
#pragma unroll
      for (int r = 0; r < 32; ++r) {
        const int rr = r & 15;
        const int kk = (r >> 4) * 32 + (rr & 3) + 8 * (rr >> 2) + 4 * g;
        if (mask[(size_t)bb * TT + kt * 64 + kk]) p[r] += -1e30f;
      }
    }

    // row max over 64 keys: in-lane tree + cross-half
    float tv[32];
#pragma unroll
    for (int i = 0; i < 32; ++i) tv[i] = p[i];
#pragma unroll
    for (int st = 16; st >= 1; st >>= 1)
#pragma unroll
      for (int i = 0; i < st; ++i) tv[i] = fmaxf(tv[i], tv[i + st]);
    float pmax = fmaxf(tv[0], __shfl_xor(tv[0], 32));

    if (kt == 0) {
      m_run = pmax;
    } else if (!__all(pmax - m_run <= 8.0f)) {
      // rescale slow path (defer-max threshold exceeded)
      const float nm = fmaxf(m_run, pmax);
      const float sc = __expf(m_run - nm);
      m_run = nm;
      l_run *= sc;
      if (lane < 32) psc[wave][l31] = sc;
      asm volatile("s_waitcnt lgkmcnt(0)" ::: "memory");
#pragma unroll
      for (int r = 0; r < 16; ++r) {
        const float s = psc[wave][(r & 3) + 8 * (r >> 2) + 4 * g];
        oa0[r] *= s; oa1[r] *= s;
      }
    }

    // P = exp(S - m), row-sum
#pragma unroll
    for (int i = 0; i < 32; ++i) p[i] = __expf(p[i] - m_run);
#pragma unroll
    for (int i = 0; i < 32; ++i) tv[i] = p[i];
#pragma unroll
    for (int st = 16; st >= 1; st >>= 1)
#pragma unroll
      for (int i = 0; i < st; ++i) tv[i] += tv[i + st];
    l_run += tv[0] + __shfl_xor(tv[0], 32);

    // P -> bf16 A-frags in-register
    bf16x8 pa[4];
    p_to_frags(p, hi, &pa[0], &pa[1]);
    p_to_frags(p + 16, hi, &pa[2], &pa[3]);

    // O += P V  (Vs[d][k], B-frag = V[k][d])
#pragma unroll
    for (int ks = 0; ks < 4; ++ks) {
      const int cb = ks * 32 + g * 16;
      const bf16x8 vb0 = lds16(Vs, l31, cb);
      const bf16x8 vb1 = lds16(Vs, 32 + l31, cb);
      oa0 = __builtin_amdgcn_mfma_f32_32x32x16_bf16(pa[ks], vb0, oa0, 0, 0, 0);
      oa1 = __builtin_amdgcn_mfma_f32_32x32x16_bf16(pa[ks], vb1, oa1, 0, 0, 0);
    }
    __syncthreads();
  }

  // epilogue: O[q][d] / l
  const float linv = 1.0f / l_run;  // valid for q = l31
#pragma unroll
  for (int r = 0; r < 16; ++r) {
    const int qr = (r & 3) + 8 * (r >> 2) + 4 * g;
    const float lv = __shfl(linv, (lane & 32) | qr, 64);
    const int trow = q0 + qr;
    const size_t orow = ((size_t)bb * TT + trow) * 512 + hh * 64 + l31;
    o[orow]      = f2b(oa0[r] * lv);
    o[orow + 32] = f2b(oa1[r] * lv);
  }
}

extern "C" void kernel_launch(void* const* d_in, const int* in_sizes, int n_in,
                              void* d_out, int out_size, void* d_ws, size_t ws_size,
                              hipStream_t stream) {
  (void)in_sizes; (void)n_in; (void)out_size; (void)ws_size;
  const float* x = (const float*)d_in[0];
  const unsigned char* mask = (const unsigned char*)d_in[1];
  const float* ln_w = (const float*)d_in[2];
  const float* ln_b = (const float*)d_in[3];
  const float* w_qkv = (const float*)d_in[4];
  const float* b_qkv = (const float*)d_in[5];
  const float* w_o = (const float*)d_in[6];
  const float* b_o = (const float*)d_in[7];
  float* out = (float*)d_out;

  char* ws = (char*)d_ws;
  short* h_buf = (short*)(ws);                 // 16384*512 bf16 = 16 MB; reused as attn_out
  short* wqkvT = (short*)(ws + 16777216);      // 1536*512 bf16
  short* woT   = (short*)(ws + 18350080);      // 512*512 bf16
  short* q_ws  = (short*)(ws + 18874368);      // [64][2048][64] bf16
  short* k_ws  = (short*)(ws + 35651584);      // [64][2048][64] bf16
  short* vt_ws = (short*)(ws + 52428800);      // [64][64][2048] bf16

  hipLaunchKernelGGL(tcast_kernel, dim3(3072), dim3(256), 0, stream, w_qkv, wqkvT, 1536);
  hipLaunchKernelGGL(tcast_kernel, dim3(1024), dim3(256), 0, stream, w_o, woT, 512);
  hipLaunchKernelGGL(ln_kernel, dim3(16384), dim3(256), 0, stream, x, ln_w, ln_b, h_buf);
  hipLaunchKernelGGL((gemm128_kernel<0>), dim3(128, 12), dim3(256), 0, stream,
                     h_buf, wqkvT, b_qkv, (void*)q_ws, (void*)k_ws, (void*)vt_ws);
  hipLaunchKernelGGL(rope_kernel, dim3(16384), dim3(256), 0, stream, q_ws, k_ws);
  hipLaunchKernelGGL(attn_kernel, dim3(16, 64), dim3(256), 0, stream,
                     q_ws, k_ws, vt_ws, mask, h_buf);
  hipLaunchKernelGGL((gemm128_kernel<1>), dim3(128, 4), dim3(256), 0, stream,
                     h_buf, woT, b_o, (void*)out, nullptr, nullptr);
}

// Round 3
// 216.601 us; speedup vs baseline: 1.5068x; 1.0774x over previous
//
#include <hip/hip_runtime.h>
#include <hip/hip_bf16.h>

#define TT 2048

typedef __attribute__((ext_vector_type(8))) short bf16x8;
typedef __attribute__((ext_vector_type(4))) float f32x4;
typedef __attribute__((ext_vector_type(16))) float f32x16;
typedef __attribute__((ext_vector_type(2))) int i32x2;

__device__ __forceinline__ short f2b(float f) {
  union { float f; unsigned u; } a; a.f = f;
  unsigned r = a.u + 0x7fffu + ((a.u >> 16) & 1u);
  return (short)(r >> 16);
}
__device__ __forceinline__ float b2f(short s) {
  union { unsigned u; float f; } a; a.u = ((unsigned)(unsigned short)s) << 16;
  return a.f;
}
__device__ __forceinline__ unsigned cvtpk(float lo, float hi) {
  unsigned r;
  asm("v_cvt_pk_bf16_f32 %0, %1, %2" : "=v"(r) : "v"(lo), "v"(hi));
  return r;
}
__device__ __forceinline__ float max3f(float a, float b, float c) {
  float d;
  asm("v_max3_f32 %0, %1, %2, %3" : "=v"(d) : "v"(a), "v"(b), "v"(c));
  return d;
}
__device__ __forceinline__ float ex2(float x) {
#if __has_builtin(__builtin_amdgcn_exp2f)
  return __builtin_amdgcn_exp2f(x);
#else
  return exp2f(x);
#endif
}
// exchange high-32 lanes of a with low-32 lanes of b
__device__ __forceinline__ void swap_halves(unsigned &a, unsigned &b, bool hi) {
#if __has_builtin(__builtin_amdgcn_permlane32_swap)
  i32x2 r = __builtin_amdgcn_permlane32_swap((int)a, (int)b, false, false);
  a = (unsigned)r[0]; b = (unsigned)r[1];
#else
  unsigned as = (unsigned)__shfl_xor((int)a, 32);
  unsigned bs = (unsigned)__shfl_xor((int)b, 32);
  unsigned na = hi ? bs : a;
  unsigned nb = hi ? b : as;
  a = na; b = nb;
#endif
}

// 16 f32 P-values (one 32-row S^T fragment) -> two PV A-frags
__device__ __forceinline__ void p_to_frags(const f32x16 p, bool hi, bf16x8* f0, bf16x8* f1) {
  unsigned A[4][2];
#pragma unroll
  for (int u = 0; u < 4; ++u)
#pragma unroll
    for (int c = 0; c < 2; ++c)
      A[u][c] = cvtpk(p[4 * u + 2 * c], p[4 * u + 2 * c + 1]);
  swap_halves(A[0][0], A[1][0], hi);
  swap_halves(A[0][1], A[1][1], hi);
  swap_halves(A[2][0], A[3][0], hi);
  swap_halves(A[2][1], A[3][1], hi);
  union { unsigned u[4]; bf16x8 v; } r0, r1;
  r0.u[0] = A[0][0]; r0.u[1] = A[0][1]; r0.u[2] = A[1][0]; r0.u[3] = A[1][1];
  r1.u[0] = A[2][0]; r1.u[1] = A[2][1]; r1.u[2] = A[3][0]; r1.u[3] = A[3][1];
  *f0 = r0.v; *f1 = r1.v;
}

__device__ __forceinline__ bf16x8 lds16(const short* base, int row, int cb) {
  return *reinterpret_cast<const bf16x8*>(
      reinterpret_cast<const char*>(base) + row * 128 + (cb ^ ((row & 7) << 4)));
}
__device__ __forceinline__ void lds16w(short* base, int row, int cb, bf16x8 v) {
  *reinterpret_cast<bf16x8*>(
      reinterpret_cast<char*>(base) + row * 128 + (cb ^ ((row & 7) << 4))) = v;
}

// dst[n][k] = bf16(src[k][n]);  K fixed at 512
__global__ __launch_bounds__(256) void tcast_kernel(const float* __restrict__ src,
                                                    short* __restrict__ dst, int N) {
  int idx = blockIdx.x * 256 + threadIdx.x;
  int n = idx >> 9, kk = idx & 511;
  if (n < N) dst[idx] = f2b(src[(size_t)kk * N + n]);
}

// LayerNorm rows of 512, fp32 in, bf16 out
__global__ __launch_bounds__(256) void ln_kernel(const float* __restrict__ x,
                                                 const float* __restrict__ w,
                                                 const float* __restrict__ b,
                                                 short* __restrict__ h) {
  const int row = blockIdx.x;
  const int tid = threadIdx.x;
  const float2 v = *reinterpret_cast<const float2*>(x + (size_t)row * 512 + tid * 2);
  float s = v.x + v.y;
  float sq = v.x * v.x + v.y * v.y;
  for (int off = 1; off < 64; off <<= 1) { s += __shfl_xor(s, off); sq += __shfl_xor(sq, off); }
  __shared__ float red[8];
  const int wv = tid >> 6;
  if ((tid & 63) == 0) { red[wv] = s; red[wv + 4] = sq; }
  __syncthreads();
  s = red[0] + red[1] + red[2] + red[3];
  sq = red[4] + red[5] + red[6] + red[7];
  const float mu = s * (1.0f / 512.0f);
  const float var = sq * (1.0f / 512.0f) - mu * mu;
  const float inv = rsqrtf(var + 1e-5f);
  const float2 wv2 = *reinterpret_cast<const float2*>(w + tid * 2);
  const float2 bv2 = *reinterpret_cast<const float2*>(b + tid * 2);
  const float h0 = (v.x - mu) * inv * wv2.x + bv2.x;
  const float h1 = (v.y - mu) * inv * wv2.y + bv2.y;
  unsigned u = (unsigned)(unsigned short)f2b(h0) | ((unsigned)(unsigned short)f2b(h1) << 16);
  *reinterpret_cast<unsigned*>(h + (size_t)row * 512 + tid * 2) = u;
}

// 128x128 tile GEMM, A[M][512] bf16 row-major, Bt[N][512] bf16 (B transposed).
template <int EPI>
__global__ __launch_bounds__(256) void gemm128_kernel(const short* __restrict__ A,
                                                      const short* __restrict__ Bt,
                                                      const float* __restrict__ bias,
                                                      void* __restrict__ o0,
                                                      void* __restrict__ o1,
                                                      void* __restrict__ o2) {
  __shared__ short As[128][72];
  __shared__ short Bs[128][72];
  const int tid = threadIdx.x;
  const int lane = tid & 63, wave = tid >> 6;
  const int lr = lane & 15, lg = lane >> 4;
  const int wm = wave >> 1, wn = wave & 1;
  const int m0 = blockIdx.x * 128, n0 = blockIdx.y * 128;
  const int sr = tid >> 3, sc = (tid & 7) * 8;

  f32x4 acc[4][4] = {};

  for (int k0 = 0; k0 < 512; k0 += 64) {
    for (int i = 0; i < 4; ++i) {
      const int r = sr + 32 * i;
      *reinterpret_cast<bf16x8*>(&As[r][sc]) =
          *reinterpret_cast<const bf16x8*>(A + (size_t)(m0 + r) * 512 + k0 + sc);
      *reinterpret_cast<bf16x8*>(&Bs[r][sc]) =
          *reinterpret_cast<const bf16x8*>(Bt + (size_t)(n0 + r) * 512 + k0 + sc);
    }
    __syncthreads();
    for (int ks = 0; ks < 2; ++ks) {
      bf16x8 af[4], bfr[4];
      for (int m = 0; m < 4; ++m)
        af[m] = *reinterpret_cast<const bf16x8*>(&As[wm * 64 + m * 16 + lr][ks * 32 + lg * 8]);
      for (int n = 0; n < 4; ++n)
        bfr[n] = *reinterpret_cast<const bf16x8*>(&Bs[wn * 64 + n * 16 + lr][ks * 32 + lg * 8]);
      for (int m = 0; m < 4; ++m)
        for (int n = 0; n < 4; ++n)
          acc[m][n] = __builtin_amdgcn_mfma_f32_16x16x32_bf16(af[m], bfr[n], acc[m][n], 0, 0, 0);
    }
    __syncthreads();
  }

  for (int m = 0; m < 4; ++m) {
    for (int n = 0; n < 4; ++n) {
      for (int j = 0; j < 4; ++j) {
        const int row = m0 + wm * 64 + m * 16 + lg * 4 + j;
        const int col = n0 + wn * 64 + n * 16 + lr;
        const float val = acc[m][n][j] + bias[col];
        if (EPI == 0) {
          const int which = col >> 9;
          const int rem = col & 511;
          const int hh = rem >> 6, d = rem & 63;
          const int bb = row >> 11, t = row & 2047;
          const int bh = bb * 8 + hh;
          short* qp = (short*)o0; short* kp = (short*)o1; short* vtp = (short*)o2;
          if (which == 0)      qp[((size_t)bh * TT + t) * 64 + d] = f2b(val);
          else if (which == 1) kp[((size_t)bh * TT + t) * 64 + d] = f2b(val);
          else                 vtp[((size_t)bh * 64 + d) * TT + t] = f2b(val);
        } else {
          float* outp = (float*)o0;
          outp[(size_t)row * 512 + col] = val;
        }
      }
    }
  }
}

// RoPE in-place on q and k, layout [bh][t][64]; q scaled by log2(e)/sqrt(64)
__global__ __launch_bounds__(256) void rope_kernel(short* __restrict__ q, short* __restrict__ k) {
  const unsigned idx = blockIdx.x * 256 + threadIdx.x;  // 64*2048*32 total
  const int i = idx & 31;
  const unsigned bt = idx >> 5;
  const int t = bt & 2047;
  const float inv_freq = __expf(-(float)i * (9.210340371976184f / 32.0f));  // 10000^(-i/32)
  const float ang = (float)t * inv_freq;
  float sv, cv;
  sincosf(ang, &sv, &cv);
  const size_t base = (size_t)bt * 64;
  const float QS = 0.125f * 1.4426950408889634f;  // fold 1/sqrt(dk) * log2(e) into q
  {
    const float x1 = b2f(q[base + i]), x2 = b2f(q[base + i + 32]);
    q[base + i]      = f2b((x1 * cv - x2 * sv) * QS);
    q[base + i + 32] = f2b((x2 * cv + x1 * sv) * QS);
  }
  {
    const float x1 = b2f(k[base + i]), x2 = b2f(k[base + i + 32]);
    k[base + i]      = f2b(x1 * cv - x2 * sv);
    k[base + i + 32] = f2b(x2 * cv + x1 * sv);
  }
}

// Flash attention, swapped-QK^T 32x32x16, exp2-domain softmax, 2-phase dbuf pipeline.
// grid: 1024 linear blocks (XCD-swizzled); 4 waves x 32 q-rows.
__global__ __launch_bounds__(256) void attn_kernel(const short* __restrict__ q,
                                                   const short* __restrict__ k,
                                                   const short* __restrict__ vt,
                                                   const unsigned char* __restrict__ mask,
                                                   short* __restrict__ o) {
  __shared__ short Ks[2][64 * 64];
  __shared__ short Vs[2][64 * 64];
  __shared__ float psc[4][32];
  const int tid = threadIdx.x;
  const int lane = tid & 63, wave = tid >> 6;
  const int l31 = lane & 31, g = lane >> 5;
  const bool hi = (g != 0);
  // bijective XCD swizzle: 1024 blocks, 8 XCDs -> 16 q-tiles of one bh stay on one XCD
  const int nb = (blockIdx.x & 7) * 128 + (blockIdx.x >> 3);
  const int bh = nb >> 4, qt = nb & 15;
  const int bb = bh >> 3, hh = bh & 7;
  const int q0 = qt * 128 + wave * 32;
  const size_t bhT = (size_t)bh * TT;
  const unsigned char* maskb = mask + (size_t)bb * TT;

  // Q as B-operand frags
  bf16x8 qf[4];
#pragma unroll
  for (int ds = 0; ds < 4; ++ds)
    qf[ds] = *reinterpret_cast<const bf16x8*>(q + (bhT + q0 + l31) * 64 + ds * 16 + g * 8);

  f32x16 oa0 = {}, oa1 = {};
  float m_run = 0.0f, l_run = 0.0f;

  const int srow = tid >> 2;         // 0..63
  const int scb = (tid & 3) * 32;    // byte col in 128B row

  const char* kgp = (const char*)(k + (bhT + srow) * 64);
  const char* vgp = (const char*)(vt + ((size_t)bh * 64 + srow) * TT);

  // prologue: stage tile 0
  bf16x8 sa = *(const bf16x8*)(kgp + scb);
  bf16x8 sb = *(const bf16x8*)(kgp + scb + 16);
  bf16x8 sc2 = *(const bf16x8*)(vgp + scb);
  bf16x8 sd = *(const bf16x8*)(vgp + scb + 16);
  kgp += 8192; vgp += 128;
  lds16w(Ks[0], srow, scb, sa);
  lds16w(Ks[0], srow, scb + 16, sb);
  lds16w(Vs[0], srow, scb, sc2);
  lds16w(Vs[0], srow, scb + 16, sd);
  __syncthreads();

  unsigned mq = 0;
  for (int kt = 0; kt < TT / 64; ++kt) {
    const int cur = kt & 1;
    if (kt < TT / 64 - 1) {  // issue next tile's loads early (latency hides under compute)
      sa = *(const bf16x8*)(kgp + scb);
      sb = *(const bf16x8*)(kgp + scb + 16);
      sc2 = *(const bf16x8*)(vgp + scb);
      sd = *(const bf16x8*)(vgp + scb + 16);
      kgp += 8192; vgp += 128;
    }
    if ((kt & 3) == 0) mq = *(const unsigned*)(maskb + kt * 64 + lane * 4);

    const short* Kc = Ks[cur];
    const short* Vc = Vs[cur];

    // S^T = K Q^T
    f32x16 s0 = {}, s1 = {};
    __builtin_amdgcn_s_setprio(1);
#pragma unroll
    for (int ds = 0; ds < 4; ++ds) {
      const int cb = ds * 32 + g * 16;
      const bf16x8 ka0 = lds16(Kc, l31, cb);
      const bf16x8 ka1 = lds16(Kc, 32 + l31, cb);
      s0 = __builtin_amdgcn_mfma_f32_32x32x16_bf16(ka0, qf[ds], s0, 0, 0, 0);
      s1 = __builtin_amdgcn_mfma_f32_32x32x16_bf16(ka1, qf[ds], s1, 0, 0, 0);
    }
    __builtin_amdgcn_s_setprio(0);

    if (__any((int)(mq != 0))) {  // slow path: apply mask elementwise
#pragma unroll
      for (int r = 0; r < 16; ++r) {
        const int kk = (r & 3) + 8 * (r >> 2) + 4 * g;
        if (maskb[kt * 64 + kk]) s0[r] += -1e30f;
        if (maskb[kt * 64 + 32 + kk]) s1[r] += -1e30f;
      }
    }

    // row max over 64 keys: max3 tree + cross-half
    float b8[8];
#pragma unroll
    for (int i = 0; i < 8; ++i) b8[i] = max3f(s0[i], s0[i + 8], s1[i]);
    float c4[4];
#pragma unroll
    for (int i = 0; i < 4; ++i) c4[i] = fmaxf(s1[8 + i], s1[12 + i]);
    const float d0 = max3f(b8[0], b8[1], b8[2]);
    const float d1 = max3f(b8[3], b8[4], b8[5]);
    const float d2 = max3f(b8[6], b8[7], c4[0]);
    const float d3 = max3f(c4[1], c4[2], c4[3]);
    const float mx = fmaxf(max3f(d0, d1, d2), d3);
    const float pmax = fmaxf(mx, __shfl_xor(mx, 32));

    if (kt == 0) {
      m_run = pmax;
    } else if (!__all((int)(pmax - m_run <= 8.0f))) {
      const float nm = fmaxf(m_run, pmax);
      const float sc = ex2(m_run - nm);
      m_run = nm;
      l_run *= sc;
      if (lane < 32) psc[wave][l31] = sc;
      asm volatile("s_waitcnt lgkmcnt(0)" ::: "memory");
#pragma unroll
      for (int r = 0; r < 16; ++r) {
        const float s = psc[wave][(r & 3) + 8 * (r >> 2) + 4 * g];
        oa0[r] *= s; oa1[r] *= s;
      }
    }

    // P = exp2(S - m) in place
#pragma unroll
    for (int i = 0; i < 16; ++i) { s0[i] = ex2(s0[i] - m_run); s1[i] = ex2(s1[i] - m_run); }

    // row sum (pairwise tree)
    float a8[8];
#pragma unroll
    for (int i = 0; i < 8; ++i) a8[i] = (s0[i] + s0[i + 8]) + (s1[i] + s1[i + 8]);
    const float e0 = (a8[0] + a8[1]) + (a8[2] + a8[3]);
    const float e1 = (a8[4] + a8[5]) + (a8[6] + a8[7]);
    const float rsum = e0 + e1;
    l_run += rsum + __shfl_xor(rsum, 32);

    // P -> bf16 A-frags in-register
    bf16x8 pa[4];
    p_to_frags(s0, hi, &pa[0], &pa[1]);
    p_to_frags(s1, hi, &pa[2], &pa[3]);

    // O += P V
    __builtin_amdgcn_s_setprio(1);
#pragma unroll
    for (int ks = 0; ks < 4; ++ks) {
      const int cb = ks * 32 + g * 16;
      const bf16x8 vb0 = lds16(Vc, l31, cb);
      const bf16x8 vb1 = lds16(Vc, 32 + l31, cb);
      oa0 = __builtin_amdgcn_mfma_f32_32x32x16_bf16(pa[ks], vb0, oa0, 0, 0, 0);
      oa1 = __builtin_amdgcn_mfma_f32_32x32x16_bf16(pa[ks], vb1, oa1, 0, 0, 0);
    }
    __builtin_amdgcn_s_setprio(0);

    // write next tile to the other buffer, then single barrier
    if (kt < TT / 64 - 1) {
      const int nxt = cur ^ 1;
      lds16w(Ks[nxt], srow, scb, sa);
      lds16w(Ks[nxt], srow, scb + 16, sb);
      lds16w(Vs[nxt], srow, scb, sc2);
      lds16w(Vs[nxt], srow, scb + 16, sd);
    }
    __syncthreads();
  }

  // epilogue: O[q][d] / l
  const float linv = 1.0f / l_run;  // valid for q = l31
#pragma unroll
  for (int r = 0; r < 16; ++r) {
    const int qr = (r & 3) + 8 * (r >> 2) + 4 * g;
    const float lv = __shfl(linv, (lane & 32) | qr, 64);
    const int trow = q0 + qr;
    const size_t orow = ((size_t)bb * TT + trow) * 512 + hh * 64 + l31;
    o[orow]      = f2b(oa0[r] * lv);
    o[orow + 32] = f2b(oa1[r] * lv);
  }
}

extern "C" void kernel_launch(void* const* d_in, const int* in_sizes, int n_in,
                              void* d_out, int out_size, void* d_ws, size_t ws_size,
                              hipStream_t stream) {
  (void)in_sizes; (void)n_in; (void)out_size; (void)ws_size;
  const float* x = (const float*)d_in[0];
  const unsigned char* mask = (const unsigned char*)d_in[1];
  const float* ln_w = (const float*)d_in[2];
  const float* ln_b = (const float*)d_in[3];
  const float* w_qkv = (const float*)d_in[4];
  const float* b_qkv = (const float*)d_in[5];
  const float* w_o = (const float*)d_in[6];
  const float* b_o = (const float*)d_in[7];
  float* out = (float*)d_out;

  char* ws = (char*)d_ws;
  short* h_buf = (short*)(ws);                 // 16384*512 bf16 = 16 MB; reused as attn_out
  short* wqkvT = (short*)(ws + 16777216);      // 1536*512 bf16
  short* woT   = (short*)(ws + 18350080);      // 512*512 bf16
  short* q_ws  = (short*)(ws + 18874368);      // [64][2048][64] bf16
  short* k_ws  = (short*)(ws + 35651584);      // [64][2048][64] bf16
  short* vt_ws = (short*)(ws + 52428800);      // [64][64][2048] bf16

  hipLaunchKernelGGL(tcast_kernel, dim3(3072), dim3(256), 0, stream, w_qkv, wqkvT, 1536);
  hipLaunchKernelGGL(tcast_kernel, dim3(1024), dim3(256), 0, stream, w_o, woT, 512);
  hipLaunchKernelGGL(ln_kernel, dim3(16384), dim3(256), 0, stream, x, ln_w, ln_b, h_buf);
  hipLaunchKernelGGL((gemm128_kernel<0>), dim3(128, 12), dim3(256), 0, stream,
                     h_buf, wqkvT, b_qkv, (void*)q_ws, (void*)k_ws, (void*)vt_ws);
  hipLaunchKernelGGL(rope_kernel, dim3(16384), dim3(256), 0, stream, q_ws, k_ws);
  hipLaunchKernelGGL(attn_kernel, dim3(1024), dim3(256), 0, stream,
                     q_ws, k_ws, vt_ws, mask, h_buf);
  hipLaunchKernelGGL((gemm128_kernel<1>), dim3(128, 4), dim3(256), 0, stream,
                     h_buf, woT, b_o, (void*)out, nullptr, nullptr);
}